// Round 1
// 314.941 us; speedup vs baseline: 1.0392x; 1.0392x over previous
//
#include <hip/hip_runtime.h>
#include <hip/hip_bf16.h>
#include <cstdint>
#include <math.h>

// Problem constants
#define S_LEN   2048
#define B_SZ    2
#define D_MODEL 2048
#define NH      16
#define NKV     4
#define HD      128
#define ROWS    (S_LEN * B_SZ)          // 4096
#define NQKV    3072                    // NH*HD + 2*NKV*HD
#define SCALE   0.08838834764831845f    // 1/sqrt(HD)

typedef __attribute__((ext_vector_type(8))) short short8;   // 8 bf16 = 4 VGPRs
typedef __attribute__((ext_vector_type(4))) float f32x4;    // MFMA acc

__device__ __forceinline__ short f2bf(float f) {
  union { float f; unsigned u; } v; v.f = f;
  unsigned r = v.u + 0x7fffu + ((v.u >> 16) & 1u);   // RNE
  return (short)(r >> 16);
}
__device__ __forceinline__ float bf2f(short x) {
  union { unsigned u; float f; } v;
  v.u = ((unsigned)(unsigned short)x) << 16;
  return v.f;
}

// async global->LDS 16B: dest is wave-uniform base + lane*16 (m104/m108 caveat)
__device__ __forceinline__ void async16(const short* g, short* l) {
  __builtin_amdgcn_global_load_lds(
      (const __attribute__((address_space(1))) void*)(uintptr_t)(const void*)g,
      (__attribute__((address_space(3))) void*)(uintptr_t)(void*)l,
      16, 0, 0);
}

// ---------------- fp32 -> bf16 elementwise (x) ----------------
__global__ void cvt_bf16_kernel(const float* __restrict__ src, short* __restrict__ dst, int n4) {
  int t = blockIdx.x * blockDim.x + threadIdx.x;
  if (t >= n4) return;
  float4 v = ((const float4*)src)[t];
  short4 o;
  o.x = f2bf(v.x); o.y = f2bf(v.y); o.z = f2bf(v.z); o.w = f2bf(v.w);
  *(short4*)(dst + (size_t)t * 4) = o;
}

// ------- fp32 [2048][N] -> bf16 transposed; Wq/Wk/Wv merged in one launch -------
__global__ void wtrans_qkv_kernel(const float* __restrict__ Wq,
                                  const float* __restrict__ Wk,
                                  const float* __restrict__ Wv,
                                  short* __restrict__ dst) {
  __shared__ float tile[32][33];
  const int bx = blockIdx.x;
  const float* src;
  int Ndim, n0, drow;
  if (bx < 64)      { src = Wq; Ndim = 2048; n0 = bx * 32;        drow = n0; }
  else if (bx < 80) { src = Wk; Ndim = 512;  n0 = (bx - 64) * 32; drow = 2048 + n0; }
  else              { src = Wv; Ndim = 512;  n0 = (bx - 80) * 32; drow = 2560 + n0; }
  const int k0 = blockIdx.y * 32;
  for (int r = threadIdx.y; r < 32; r += 8)
    tile[r][threadIdx.x] = src[(size_t)(k0 + r) * Ndim + n0 + threadIdx.x];
  __syncthreads();
  for (int r = threadIdx.y; r < 32; r += 8)
    dst[(size_t)(drow + r) * 2048 + k0 + threadIdx.x] = f2bf(tile[threadIdx.x][r]);
}

__global__ void wtrans_kernel(const float* __restrict__ src, short* __restrict__ dst,
                              int Kdim, int Ndim) {
  __shared__ float tile[32][33];
  int n0 = blockIdx.x * 32, k0 = blockIdx.y * 32;
  for (int r = threadIdx.y; r < 32; r += 8)
    tile[r][threadIdx.x] = src[(size_t)(k0 + r) * Ndim + n0 + threadIdx.x];
  __syncthreads();
  for (int r = threadIdx.y; r < 32; r += 8)
    dst[(size_t)(n0 + r) * Kdim + k0 + threadIdx.x] = f2bf(tile[threadIdx.x][r]);
}

// ================= deep-pipelined GEMM: C[M][N] = A[M][K] @ Bt[N][K]^T =========
// BN=256 fixed, BM in {128,256}. 512 threads = 8 waves (2m x 4n).
// BK=32, linear LDS (64B row pitch -> frag ds_read_b128 is bank-conflict-free,
// so global_load_lds direct staging works without swizzle).
// 4-deep LDS ring; counted vmcnt (2 tiles always in flight; never 0 in loop);
// raw s_barrier; setprio(1) around each 16-MFMA cluster; XCD block swizzle.
template<int BM, int BF16OUT>
__global__ __launch_bounds__(512, 2) void gemm2_kernel(const short* __restrict__ A,
    const short* __restrict__ Bt, void* __restrict__ Cv, int N, int K) {
  constexpr int MI  = BM / 32;       // m-frags per wave (4 or 8)
  constexpr int PH  = MI / 4;        // phases per K-tile (1 or 2)
  constexpr int APW = BM / 128;      // A stage calls per wave per tile (1 or 2)
  constexpr int TC  = APW + 2;       // total stage calls per wave per tile
  constexpr int ASZ = BM * 32;       // shorts per A tile
  constexpr int BSZ = 256 * 32;      // shorts per B tile
  constexpr int BUFS = ASZ + BSZ;
  __shared__ alignas(16) short lds[4 * BUFS];   // 96KB (BM=128) / 128KB (BM=256)

  const int tid  = threadIdx.x;
  const int w    = tid >> 6, lane = tid & 63;
  const int quad = lane >> 4, lr = lane & 15;
  const int wm   = w >> 2, wn = w & 3;

  // XCD-aware bijective swizzle (both call sites have gridDim.x % 8 == 0)
  const int nwg = gridDim.x;
  const int id  = (blockIdx.x & 7) * (nwg >> 3) + (blockIdx.x >> 3);
  const int nbx = N >> 8;                 // N / 256
  const int bx = id % nbx, by = id / nbx;
  const int m0 = by * BM, n0 = bx * 256;

  // staging source pointers: call covers 16 rows, lane -> (row = l>>2, 16B chunk = l&3)
  const short* gA = A  + (size_t)(m0 + w * (16 * APW) + (lane >> 2)) * K + (lane & 3) * 8;
  const short* gB = Bt + (size_t)(n0 + w * 32 + (lane >> 2)) * K + (lane & 3) * 8;

  // fragment read offsets (shorts): row-major [rows][32] per tile
  const int aoff = (wm * (BM / 2) + lr) * 32 + quad * 8;
  const int boff = (wn * 64 + lr) * 32 + quad * 8;

  f32x4 acc[MI][4];
#pragma unroll
  for (int i = 0; i < MI; ++i)
#pragma unroll
    for (int j = 0; j < 4; ++j) acc[i][j] = (f32x4){0.f, 0.f, 0.f, 0.f};

  auto stageA = [&](int t) {
    short* la = lds + (t & 3) * BUFS;
    const short* g = gA + t * 32;
#pragma unroll
    for (int c = 0; c < APW; ++c)
      async16(g + (size_t)c * 16 * K, la + (w * APW + c) * 512);
  };
  auto stageB = [&](int t) {
    short* lb = lds + (t & 3) * BUFS + ASZ;
    const short* g = gB + t * 32;
#pragma unroll
    for (int c = 0; c < 2; ++c)
      async16(g + (size_t)c * 16 * K, lb + (w * 2 + c) * 512);
  };

  const int NT = K >> 5;
  // prologue: 3 tiles issued; wait until tile 0 landed (2 tiles stay in flight)
  stageA(0); stageB(0); stageA(1); stageB(1); stageA(2); stageB(2);
  asm volatile("s_waitcnt vmcnt(%0)" :: "n"(2 * TC) : "memory");
  __builtin_amdgcn_s_barrier();

  for (int t = 0; t < NT; ++t) {
    const short* la = lds + (t & 3) * BUFS;
    const short* lb = la + ASZ;
    const bool pre = (t + 3) < NT;

    // ---- phase 0: m-frags 0..3 x all n (16 MFMA) ----
    short8 a0[4], b0[4];
#pragma unroll
    for (int j = 0; j < 4; ++j) b0[j] = *(const short8*)(lb + boff + j * 512);
#pragma unroll
    for (int i = 0; i < 4; ++i) a0[i] = *(const short8*)(la + aoff + i * 512);
    if (pre) stageA(t + 3);              // writes buf (t-1)&3: reads done at t-1's last barrier
    if (PH == 1 && pre) stageB(t + 3);
    __builtin_amdgcn_s_barrier();
    __builtin_amdgcn_s_setprio(1);
#pragma unroll
    for (int i = 0; i < 4; ++i)
#pragma unroll
      for (int j = 0; j < 4; ++j)
        acc[i][j] = __builtin_amdgcn_mfma_f32_16x16x32_bf16(a0[i], b0[j], acc[i][j], 0, 0, 0);
    __builtin_amdgcn_s_setprio(0);

    if (PH == 2) {
      __builtin_amdgcn_s_barrier();
      // ---- phase 1: m-frags 4..7 (B frags kept in registers) ----
      short8 a1[4];
#pragma unroll
      for (int i = 0; i < 4; ++i) a1[i] = *(const short8*)(la + aoff + (4 + i) * 512);
      if (pre) stageB(t + 3);
      __builtin_amdgcn_s_barrier();
      __builtin_amdgcn_s_setprio(1);
#pragma unroll
      for (int i = 0; i < 4; ++i)
#pragma unroll
        for (int j = 0; j < 4; ++j)
          acc[4 + i][j] = __builtin_amdgcn_mfma_f32_16x16x32_bf16(a1[i], b0[j], acc[4 + i][j], 0, 0, 0);
      __builtin_amdgcn_s_setprio(0);
    }

    // tile end: counted vmcnt (tile t+1 landed; t+2,t+3 stay in flight), then barrier
    if (t < NT - 1) {
      if (t < NT - 3)       asm volatile("s_waitcnt vmcnt(%0)" :: "n"(2 * TC) : "memory");
      else if (t == NT - 3) asm volatile("s_waitcnt vmcnt(%0)" :: "n"(TC) : "memory");
      else                  asm volatile("s_waitcnt vmcnt(0)" ::: "memory");
      __builtin_amdgcn_s_barrier();
    }
  }

  // epilogue
#pragma unroll
  for (int i = 0; i < MI; ++i) {
    const int row = m0 + wm * (BM / 2) + i * 16 + quad * 4;
#pragma unroll
    for (int j = 0; j < 4; ++j) {
      const int col = n0 + wn * 64 + j * 16 + lr;
#pragma unroll
      for (int r = 0; r < 4; ++r) {
        const float v = acc[i][j][r];
        if (BF16OUT) ((short*)Cv)[(size_t)(row + r) * N + col] = f2bf(v);
        else         ((float*)Cv)[(size_t)(row + r) * N + col] = v;
      }
    }
  }
}

// ---------------- RoPE: Q -> Qb [B][NH][S][HD] (scaled); K -> packed frags ----
// Kpack entry: [stream][tile=s/16][c=d/32][lane=quad*16+(s&15)][j=d&7]
//   = K[s][c*32+quad*8+j]  (MFMA A-operand order for the QK^T matmul)
__global__ void rope_kernel(const short* __restrict__ QKVb, short* __restrict__ Qb,
                            short* __restrict__ Kpack) {
  const int head = blockIdx.y;                              // 0..19: 0..15=Q, 16..19=K
  const int t = blockIdx.x * blockDim.x + threadIdx.x;
  const int i = t & 63;
  const int row = t >> 6;                                   // s*B + b
  const int s = row >> 1;
  const int b = row & 1;
  float inv_freq = __expf(-(float)i * (1.0f / 64.0f) * 9.210340371976184f); // theta^(-i/64)
  float ang = (float)s * inv_freq;
  float sn, cs;
  __sincosf(ang, &sn, &cs);
  if (head < NH) {
    const short* p = QKVb + (size_t)row * NQKV + head * HD;
    float v1 = bf2f(p[i]), v2 = bf2f(p[i + 64]);
    short* q = Qb + ((size_t)(b * NH + head) * S_LEN + s) * HD;
    q[i]      = f2bf((v1 * cs - v2 * sn) * SCALE);
    q[i + 64] = f2bf((v2 * cs + v1 * sn) * SCALE);
  } else {
    const int kv = head - NH;
    const short* p = QKVb + (size_t)row * NQKV + NH * HD + kv * HD;
    float v1 = bf2f(p[i]), v2 = bf2f(p[i + 64]);
    float k1 = v1 * cs - v2 * sn;
    float k2 = v2 * cs + v1 * sn;
    short* kp = Kpack + (size_t)(b * NKV + kv) * S_LEN * HD;
    const int tile = s >> 4, lrr = s & 15;
    const int d1 = i, d2 = i + 64;
    kp[(size_t)((tile * 4 + (d1 >> 5)) * 64 + ((d1 >> 3) & 3) * 16 + lrr) * 8 + (d1 & 7)] = f2bf(k1);
    kp[(size_t)((tile * 4 + (d2 >> 5)) * 64 + ((d2 >> 3) & 3) * 16 + lrr) * 8 + (d2 & 7)] = f2bf(k2);
  }
}

// ---- fused V pack: QKVb V-cols -> Vpack [stream][chunk=s/32][dt=d/16][lane][8] --
// Vpack entry (chunk,dt,lane=quad*16+lr,j) = V[s=chunk*32+quad*8+j][d=dt*16+lr]
__global__ void vpack_kernel(const short* __restrict__ QKVb, short* __restrict__ Vpack) {
  __shared__ short tile[32][136];
  const int tid = threadIdx.x;
  const int chunk = blockIdx.x & 63, stream = blockIdx.x >> 6;
  const int b = stream >> 2, kv = stream & 3;
  const int vcol = NH * HD + NKV * HD + kv * HD;
  {
    const int r = tid >> 3, c = (tid & 7) * 16;
    const short* src = QKVb + (size_t)((chunk * 32 + r) * B_SZ + b) * NQKV + vcol + c;
    *(short8*)(&tile[r][c])     = *(const short8*)(src);
    *(short8*)(&tile[r][c + 8]) = *(const short8*)(src + 8);
  }
  __syncthreads();
  const int wave = tid >> 6, lane = tid & 63, quad = lane >> 4, lr = lane & 15;
  short* dst = Vpack + (size_t)stream * HD * S_LEN + chunk * 4096 + lane * 8;
#pragma unroll
  for (int k = 0; k < 2; ++k) {
    const int dt = wave + k * 4;
    short8 v;
#pragma unroll
    for (int j = 0; j < 8; ++j) v[j] = tile[quad * 8 + j][dt * 16 + lr];
    *(short8*)(dst + dt * 512) = v;
  }
}

// ------- transposed flash attention, block-shared LDS K/V staging -------
#define PSP 72   // Ps row pitch in shorts (16B-aligned rows)

template<bool MASK>
__device__ __forceinline__ void attn_iter64(
    const short* __restrict__ Ks, const short* __restrict__ Vs,
    short* __restrict__ Psw, const short8 qf[4], int kv0, int nt, int qlim,
    int quad, int lr, int lane, f32x4 o[8], float& m_i, float& l_i)
{
  const int lane_off = lane * 8;
  // --- QK^T (transposed scores: St[kv=quad*4+r][q=lr]), K frags from LDS ---
  f32x4 sc[4];
#pragma unroll
  for (int t = 0; t < 4; ++t) {
    if (t < nt) {
      const short* kp = Ks + t * 2048 + lane_off;
      f32x4 s = (f32x4){0.f, 0.f, 0.f, 0.f};
#pragma unroll
      for (int c = 0; c < 4; ++c) {
        short8 kf = *(const short8*)(kp + c * 512);
        s = __builtin_amdgcn_mfma_f32_16x16x32_bf16(kf, qf[c], s, 0, 0, 0);
      }
      sc[t] = s;
    } else {
      sc[t] = (f32x4){-3.0e38f, -3.0e38f, -3.0e38f, -3.0e38f};
    }
  }
  // --- causal mask (tail only) ---
  if (MASK) {
#pragma unroll
    for (int t = 0; t < 4; ++t)
#pragma unroll
      for (int r = 0; r < 4; ++r)
        if (kv0 + t * 16 + quad * 4 + r > qlim) sc[t][r] = -3.0e38f;
  }
  // --- batched online softmax (per-lane column stats, q = lr) ---
  float mb = -3.0e38f;
#pragma unroll
  for (int t = 0; t < 4; ++t)
#pragma unroll
    for (int r = 0; r < 4; ++r) mb = fmaxf(mb, sc[t][r]);
  mb = fmaxf(mb, __shfl_xor(mb, 16, 64));
  mb = fmaxf(mb, __shfl_xor(mb, 32, 64));
  const float mnew = fmaxf(m_i, mb);
  const float alpha = __expf(m_i - mnew);
  m_i = mnew;
  float rs = 0.f;
#pragma unroll
  for (int t = 0; t < 4; ++t) {
    float p0 = __expf(sc[t][0] - mnew);
    float p1 = __expf(sc[t][1] - mnew);
    float p2 = __expf(sc[t][2] - mnew);
    float p3 = __expf(sc[t][3] - mnew);
    rs += (p0 + p1) + (p2 + p3);
    __hip_bfloat162 pk01 = __float22bfloat162_rn(make_float2(p0, p1));
    __hip_bfloat162 pk23 = __float22bfloat162_rn(make_float2(p2, p3));
    __hip_bfloat162* pd = (__hip_bfloat162*)(Psw + lr * PSP + t * 16 + quad * 4);
    pd[0] = pk01;
    pd[1] = pk23;
  }
  rs += __shfl_xor(rs, 16, 64);
  rs += __shfl_xor(rs, 32, 64);
  l_i = l_i * alpha + rs;
#pragma unroll
  for (int n = 0; n < 8; ++n)
#pragma unroll
    for (int r = 0; r < 4; ++r) o[n][r] *= alpha;
  // --- PV (K=32): P B-frags from wave-private LDS, V A-frags from shared LDS ---
  short8 pb0 = *(const short8*)(Psw + lr * PSP + quad * 8);
#pragma unroll
  for (int dt = 0; dt < 8; ++dt) {
    short8 vf = *(const short8*)(Vs + dt * 512 + lane_off);
    o[dt] = __builtin_amdgcn_mfma_f32_16x16x32_bf16(vf, pb0, o[dt], 0, 0, 0);
  }
  if (!MASK || nt > 2) {
    short8 pb1 = *(const short8*)(Psw + lr * PSP + 32 + quad * 8);
#pragma unroll
    for (int dt = 0; dt < 8; ++dt) {
      short8 vf = *(const short8*)(Vs + 4096 + dt * 512 + lane_off);
      o[dt] = __builtin_amdgcn_mfma_f32_16x16x32_bf16(vf, pb1, o[dt], 0, 0, 0);
    }
  }
}

__global__ __launch_bounds__(256) void attn_kernel(const short* __restrict__ Qb,
    const short* __restrict__ Kpack, const short* __restrict__ Vpack,
    short* __restrict__ Ob) {
  __shared__ alignas(16) short Ks[64 * HD];      // 16KB, Kpack frag-linear order
  __shared__ alignas(16) short Vs[64 * HD];      // 16KB, Vpack frag-linear order
  __shared__ alignas(16) short Ps[4][16 * PSP];
  const int tid = threadIdx.x, wave = tid >> 6, lane = tid & 63;
  const int quad = lane >> 4, lr = lane & 15;
  const int bid = blockIdx.x;
  const int sid  = bid & 7;           // (b,kvh) stream -> XCD L2 affinity
  const int hsub = (bid >> 3) & 3;
  const int qg   = 31 - (bid >> 5);   // heavy q-groups dispatched first
  const int b = sid >> 2, kvh = sid & 3;
  const int h = kvh * 4 + hsub;
  const int qw = (qg * 4 + wave) * 16;

  const short* Qp  = Qb    + ((size_t)(b * NH + h) * S_LEN + qw) * HD;
  const short* Kpk = Kpack + (size_t)(b * NKV + kvh) * S_LEN * HD;
  const short* Vpk = Vpack + (size_t)(b * NKV + kvh) * HD * S_LEN;
  short* Psw = &Ps[wave][0];

  // Q B-fragments (n=q=lr, k=d), loaded once
  short8 qf[4];
#pragma unroll
  for (int c = 0; c < 4; ++c)
    qf[c] = *(const short8*)(Qp + lr * HD + c * 32 + quad * 8);

  f32x4 o[8];
#pragma unroll
  for (int n = 0; n < 8; ++n) o[n] = (f32x4){0.f, 0.f, 0.f, 0.f};
  float m_i = -3.0e38f, l_i = 0.f;

  const int qlim = qw + lr;
  // uniform per-block loop: iters 0..qg-1 full, iter qg = per-wave masked tail
  for (int it = 0; it <= qg; ++it) {
    const int kv0 = it * 64;
    __syncthreads();   // previous iteration's LDS reads complete
    {
      const short* gk = Kpk + (size_t)kv0 * HD;          // tile-linear: 64kv = 16KB
      const short* gv = Vpk + (size_t)(kv0 >> 5) * 4096; // 2 chunks = 16KB
#pragma unroll
      for (int k = 0; k < 4; ++k) {
        const int off = (wave * 4 + k) * 512;            // shorts; 1KB per async16
        async16(gk + off + lane * 8, Ks + off);
        async16(gv + off + lane * 8, Vs + off);
      }
    }
    __syncthreads();   // drains vmcnt for global_load_lds
    if (it < qg)
      attn_iter64<false>(Ks, Vs, Psw, qf, kv0, 4, qlim, quad, lr, lane, o, m_i, l_i);
    else
      attn_iter64<true>(Ks, Vs, Psw, qf, kv0, wave + 1, qlim, quad, lr, lane, o, m_i, l_i);
  }

  // epilogue: lane holds O^T[d = dt*16+quad*4+r][q = qw+lr]
  const float invl = 1.0f / l_i;
  short* op = Ob + ((size_t)(qw + lr) * B_SZ + b) * D_MODEL + h * HD + quad * 4;
#pragma unroll
  for (int dt = 0; dt < 8; ++dt) {
    short4 ov;
    ov.x = f2bf(o[dt][0] * invl);
    ov.y = f2bf(o[dt][1] * invl);
    ov.z = f2bf(o[dt][2] * invl);
    ov.w = f2bf(o[dt][3] * invl);
    *(short4*)(op + dt * 16) = ov;
  }
}

// ---------------- launch ----------------
extern "C" void kernel_launch(void* const* d_in, const int* in_sizes, int n_in,
                              void* d_out, int out_size, void* d_ws, size_t ws_size,
                              hipStream_t stream) {
  (void)in_sizes; (void)n_in; (void)out_size; (void)ws_size;
  const float* x  = (const float*)d_in[0];
  const float* Wq = (const float*)d_in[1];
  const float* Wk = (const float*)d_in[2];
  const float* Wv = (const float*)d_in[3];
  const float* Wo = (const float*)d_in[4];
  float* out = (float*)d_out;
  char* ws = (char*)d_ws;

  // region A [0, 29360128): Wqkv_t(12M)+xb(16M); later Qb(16M)+Kpack(4M)+Vpack(4M)
  short* Wqkv_t = (short*)(ws);                    // [3072][2048]
  short* xb     = (short*)(ws + 12582912);         // [4096][2048]
  short* Qb     = (short*)(ws);                    // [2][16][2048][128]
  short* Kpack  = (short*)(ws + 16777216);         // packed K frags, 4MB
  short* Vpack  = (short*)(ws + 25165824);         // packed V^T frags, 4MB
  // region B [29360128, 54525952): QKVb(24M); later Ob(16M)
  short* QKVb   = (short*)(ws + 29360128);         // [4096][3072]
  short* Ob     = (short*)(ws + 29360128);         // [4096][2048]
  // region C [54525952, 62914560): Wo_t(8M)
  short* Wo_t   = (short*)(ws + 54525952);         // [2048][2048]

  dim3 tblk(32, 8);

  // 1. x -> bf16
  cvt_bf16_kernel<<<(ROWS * D_MODEL / 4 + 255) / 256, 256, 0, stream>>>(x, xb, ROWS * D_MODEL / 4);
  // 2. weight transposes to B^T layout (bf16); Wq/Wk/Wv merged
  wtrans_qkv_kernel<<<dim3(96, 64), tblk, 0, stream>>>(Wq, Wk, Wv, Wqkv_t);
  wtrans_kernel<<<dim3(64, 64), tblk, 0, stream>>>(Wo, Wo_t, 2048, 2048);
  // 3. QKV projection (bf16 out): 256x256 tiles -> 192 blocks (nwg%8==0)
  gemm2_kernel<256, 1><<<dim3((NQKV / 256) * (ROWS / 256)), 512, 0, stream>>>(xb, Wqkv_t, QKVb, NQKV, D_MODEL);
  // 4. RoPE: Q -> Qb, K -> packed frags
  rope_kernel<<<dim3(1024, NH + NKV), 256, 0, stream>>>(QKVb, Qb, Kpack);
  // 5. fused V pack (QKVb -> PV A-operand layout)
  vpack_kernel<<<dim3(512), 256, 0, stream>>>(QKVb, Vpack);
  // 6. causal flash attention (block-shared LDS staging, 4 waves/stream)
  attn_kernel<<<dim3(1024), 256, 0, stream>>>(Qb, Kpack, Vpack, Ob);
  // 7. output projection (fp32 out): 128x256 tiles -> 256 blocks (full CU coverage)
  gemm2_kernel<128, 0><<<dim3((D_MODEL / 256) * (ROWS / 128)), 512, 0, stream>>>(Ob, Wo_t, out, D_MODEL, D_MODEL);
}